// Round 8
// baseline (191.583 us; speedup 1.0000x reference)
//
#include <hip/hip_runtime.h>
#include <hip/hip_bf16.h>

typedef _Float16 h2 __attribute__((ext_vector_type(2)));

constexpr int kB = 4, kN = 256, kC = 256, kH = 8, kF = 64, kHF = 512;

union H2U { h2 h; unsigned int u; };

// ---------------------------------------------------------------------------
// Phase A: g = x @ W  (fp32 in, f16 out to ws). W selected by blockIdx.y.
// R5's proven version: LDS-staged x, W software-pipelined.
// Block: 256 threads, 4 rows x 512 cols. Grid: (256, 2).
// ---------------------------------------------------------------------------
__global__ __launch_bounds__(256) void gat_gemm_kernel(
    const float* __restrict__ x,
    const float* __restrict__ Wl,
    const float* __restrict__ Wr,
    unsigned int* __restrict__ gl,    // f16 pairs
    unsigned int* __restrict__ gr)
{
    __shared__ float xs[4][kC];   // 4 KiB
    const int rowBase = blockIdx.x * 4;
    const float* Wm = (blockIdx.y == 0) ? Wl : Wr;
    unsigned int* gout = (blockIdx.y == 0) ? gl : gr;

    const int tid = threadIdx.x;

    {
        const int r = tid >> 6;
        const int kc = (tid & 63) * 4;
        *(float4*)&xs[r][kc] = *(const float4*)(x + (rowBase + r) * kC + kc);
    }
    __syncthreads();

    const int c0 = tid * 2;
    float acc[4][2];
#pragma unroll
    for (int r = 0; r < 4; ++r) { acc[r][0] = 0.f; acc[r][1] = 0.f; }

    float2 wv[4], wn[4];
#pragma unroll
    for (int kk = 0; kk < 4; ++kk)
        wv[kk] = *(const float2*)(Wm + kk * kHF + c0);

    for (int k = 0; k < kC; k += 4) {
        if (k + 4 < kC) {
#pragma unroll
            for (int kk = 0; kk < 4; ++kk)
                wn[kk] = *(const float2*)(Wm + (k + 4 + kk) * kHF + c0);
        }
#pragma unroll
        for (int r = 0; r < 4; ++r) {
            float4 xv = *(const float4*)&xs[r][k];
            acc[r][0] = fmaf(xv.x, wv[0].x, acc[r][0]);
            acc[r][1] = fmaf(xv.x, wv[0].y, acc[r][1]);
            acc[r][0] = fmaf(xv.y, wv[1].x, acc[r][0]);
            acc[r][1] = fmaf(xv.y, wv[1].y, acc[r][1]);
            acc[r][0] = fmaf(xv.z, wv[2].x, acc[r][0]);
            acc[r][1] = fmaf(xv.z, wv[2].y, acc[r][1]);
            acc[r][0] = fmaf(xv.w, wv[3].x, acc[r][0]);
            acc[r][1] = fmaf(xv.w, wv[3].y, acc[r][1]);
        }
#pragma unroll
        for (int kk = 0; kk < 4; ++kk) wv[kk] = wn[kk];
    }

#pragma unroll
    for (int r = 0; r < 4; ++r) {
        H2U p; p.h = (h2){(_Float16)acc[r][0], (_Float16)acc[r][1]};
        gout[((rowBase + r) * kHF + c0) >> 1] = p.u;
    }
}

// ---------------------------------------------------------------------------
// Phase B v3: lane owns (j_local, h) with the FULL f=64 row in registers.
// Block = 256 threads (4 waves) per (b,i) row; grid = B*N = 1024 -> 4
// blocks/CU, 4 waves/SIMD (VGPR ~115 <= 128 via __launch_bounds__(256,4)).
// lane = jl*8 + h. Round r: lane handles j = r*32 + wv*8 + jl (8 rounds).
// e-dot: in-register fdot2 chain, ZERO f-reduce shuffles. Head softmax:
// 3 shuffles (xor 1,2,4 over h bits) amortized over 8 j's per round.
// attn_w lives in SGPRs (readfirstlane). No barrier in the j-loop.
// ---------------------------------------------------------------------------
__global__ __launch_bounds__(256, 4) void gat_attn_kernel(
    const unsigned int* __restrict__ gl,   // f16 pairs
    const unsigned int* __restrict__ gr,
    const float* __restrict__ attn_w,
    const int* __restrict__ adj,
    float* __restrict__ out)
{
    __shared__ float red[4][kHF];          // 8 KiB
    __shared__ unsigned char msk[kN];      // 256 B

    const int bi = blockIdx.x;             // b*N + i
    const int b = bi >> 8;
    const int i = bi & 255;
    const int tid = threadIdx.x;
    const int wv = tid >> 6;               // 0..3
    const int lane = tid & 63;
    const int jl = lane >> 3;              // 0..7
    const int h = lane & 7;                // 0..7

    // ---- pack adj -> LDS byte masks: msk[j] bit h = adj[i,j,h]!=0 ----
    {
        const int* ap = adj + (i * kN + tid) * kH;
        uint4 a0 = *(const uint4*)ap;
        uint4 a1 = *(const uint4*)(ap + 4);
        unsigned int m = 0;
        m |= (a0.x != 0) << 0; m |= (a0.y != 0) << 1;
        m |= (a0.z != 0) << 2; m |= (a0.w != 0) << 3;
        m |= (a1.x != 0) << 4; m |= (a1.y != 0) << 5;
        m |= (a1.z != 0) << 6; m |= (a1.w != 0) << 7;
        msk[tid] = (unsigned char)m;
    }

    // ---- gri: g_r[b, i, h, 0:64] -> 32 h2 regs ----
    h2 gri[32];
    {
        const uint4* gp = (const uint4*)(gr + (bi * 256 + h * 32));
#pragma unroll
        for (int q = 0; q < 8; ++q) {
            uint4 p = gp[q];
            H2U t;
            t.u = p.x; gri[q * 4 + 0] = t.h;
            t.u = p.y; gri[q * 4 + 1] = t.h;
            t.u = p.z; gri[q * 4 + 2] = t.h;
            t.u = p.w; gri[q * 4 + 3] = t.h;
        }
    }

    // ---- attn_w -> 32 packed-h2 SGPRs ----
    unsigned int wsg[32];
#pragma unroll
    for (int q = 0; q < 32; ++q) {
        float2 wp = *(const float2*)(attn_w + q * 2);
        H2U t; t.h = (h2){(_Float16)wp.x, (_Float16)wp.y};
        wsg[q] = __builtin_amdgcn_readfirstlane(t.u);
    }

    h2 acc[32];
#pragma unroll
    for (int q = 0; q < 32; ++q) acc[q] = (h2){(_Float16)0.f, (_Float16)0.f};

    const h2 c02 = (h2){(_Float16)0.2f, (_Float16)0.2f};

    __syncthreads();                       // msk ready

    unsigned int goff = (unsigned int)(b * kN * 256) + (wv * 8 + jl) * 256 + h * 32;
    int j = wv * 8 + jl;

    for (int round = 0; round < 8; ++round) {
        // ---- e-phase: stream g_l[b,j,h,0:64], fdot2 chain ----
        const uint4* gp = (const uint4*)(gl + goff);
        uint4 P[8];
#pragma unroll
        for (int q = 0; q < 8; ++q) P[q] = gp[q];

        float e = 0.f;
#pragma unroll
        for (int q = 0; q < 8; ++q) {
            H2U t0, t1, t2, t3, w0, w1, w2u, w3;
            t0.u = P[q].x; t1.u = P[q].y; t2.u = P[q].z; t3.u = P[q].w;
            w0.u = wsg[q * 4 + 0]; w1.u = wsg[q * 4 + 1];
            w2u.u = wsg[q * 4 + 2]; w3.u = wsg[q * 4 + 3];
            h2 s0 = gri[q * 4 + 0] + t0.h;
            h2 s1 = gri[q * 4 + 1] + t1.h;
            h2 s2 = gri[q * 4 + 2] + t2.h;
            h2 s3 = gri[q * 4 + 3] + t3.h;
            h2 u0 = __builtin_elementwise_max(s0, c02 * s0);
            h2 u1 = __builtin_elementwise_max(s1, c02 * s1);
            h2 u2 = __builtin_elementwise_max(s2, c02 * s2);
            h2 u3 = __builtin_elementwise_max(s3, c02 * s3);
            e = __builtin_amdgcn_fdot2(u0, w0.h, e, false);
            e = __builtin_amdgcn_fdot2(u1, w1.h, e, false);
            e = __builtin_amdgcn_fdot2(u2, w2u.h, e, false);
            e = __builtin_amdgcn_fdot2(u3, w3.h, e, false);
        }

        // ---- mask + head softmax (xor 1,2,4 over h lanes) ----
        const unsigned int mbit = ((unsigned int)msk[j] >> h) & 1u;
        e = mbit ? e : -1e30f;
        float ex = __expf(e);
        float den = ex;
        den += __shfl_xor(den, 1);
        den += __shfl_xor(den, 2);
        den += __shfl_xor(den, 4);
        float a = ex * __builtin_amdgcn_rcpf(den);
        h2 a2 = (h2){(_Float16)a, (_Float16)a};

        // ---- agg-phase: acc[f] += a * g_r[b,j,h,f] ----
        const uint4* gq = (const uint4*)(gr + goff);
#pragma unroll
        for (int q = 0; q < 8; ++q) {
            uint4 p = gq[q];
            H2U t0, t1, t2, t3;
            t0.u = p.x; t1.u = p.y; t2.u = p.z; t3.u = p.w;
            acc[q * 4 + 0] = __builtin_elementwise_fma(a2, t0.h, acc[q * 4 + 0]);
            acc[q * 4 + 1] = __builtin_elementwise_fma(a2, t1.h, acc[q * 4 + 1]);
            acc[q * 4 + 2] = __builtin_elementwise_fma(a2, t2.h, acc[q * 4 + 2]);
            acc[q * 4 + 3] = __builtin_elementwise_fma(a2, t3.h, acc[q * 4 + 3]);
        }

        goff += 32 * 256;
        j += 32;
    }

    // ---- butterfly-reduce acc over jl (lane bits 3,4,5), packed h2 ----
#pragma unroll
    for (int q = 0; q < 32; ++q) {
        H2U t; t.h = acc[q];
        H2U r;
        r.u = (unsigned int)__shfl_xor((int)t.u, 8);  t.h = t.h + r.h;
        r.u = (unsigned int)__shfl_xor((int)t.u, 16); t.h = t.h + r.h;
        r.u = (unsigned int)__shfl_xor((int)t.u, 32); t.h = t.h + r.h;
        acc[q] = t.h;
    }

    // lane (jl,h) owns output elements h*64 + jl*8 .. +7 (acc[jl*4..jl*4+3])
#pragma unroll
    for (int k = 0; k < 4; ++k) {
        h2 v = acc[jl * 4 + k];
        float2 f = make_float2((float)v.x, (float)v.y);
        *(float2*)&red[wv][h * 64 + jl * 8 + k * 2] = f;
    }
    __syncthreads();

    // final: 512 outputs, 256 threads -> 2 per thread
#pragma unroll
    for (int c = tid; c < kHF; c += 256) {
        float s = red[0][c] + red[1][c] + red[2][c] + red[3][c];
        out[(size_t)bi * kHF + c] = s;
    }
}

// ---------------------------------------------------------------------------
extern "C" void kernel_launch(void* const* d_in, const int* in_sizes, int n_in,
                              void* d_out, int out_size, void* d_ws, size_t ws_size,
                              hipStream_t stream) {
    const float* x  = (const float*)d_in[0];
    const float* Wl = (const float*)d_in[1];
    const float* Wr = (const float*)d_in[2];
    const float* aw = (const float*)d_in[3];
    const int* adj  = (const int*)d_in[4];

    unsigned int* gl = (unsigned int*)d_ws;                    // [B*N*HF/2]
    unsigned int* gr = gl + (size_t)kB * kN * kHF / 2;

    dim3 g1(kB * kN / 4, 2);
    gat_gemm_kernel<<<g1, 256, 0, stream>>>(x, Wl, Wr, gl, gr);

    gat_attn_kernel<<<kB * kN, 256, 0, stream>>>(
        gl, gr, aw, adj, (float*)d_out);
}

// Round 9
// 186.843 us; speedup vs baseline: 1.0254x; 1.0254x over previous
//
#include <hip/hip_runtime.h>
#include <hip/hip_bf16.h>

typedef _Float16 h2 __attribute__((ext_vector_type(2)));

constexpr int kB = 4, kN = 256, kC = 256, kH = 8, kF = 64, kHF = 512;

union H2U { h2 h; unsigned int u; };

// ---------------------------------------------------------------------------
// Phase A: g = x @ W  (fp32 in, f16 out to ws). W selected by blockIdx.y.
// R5's proven version: LDS-staged x, W software-pipelined.
// Block: 256 threads, 4 rows x 512 cols. Grid: (256, 2).
// ---------------------------------------------------------------------------
__global__ __launch_bounds__(256) void gat_gemm_kernel(
    const float* __restrict__ x,
    const float* __restrict__ Wl,
    const float* __restrict__ Wr,
    unsigned int* __restrict__ gl,    // f16 pairs
    unsigned int* __restrict__ gr)
{
    __shared__ float xs[4][kC];   // 4 KiB
    const int rowBase = blockIdx.x * 4;
    const float* Wm = (blockIdx.y == 0) ? Wl : Wr;
    unsigned int* gout = (blockIdx.y == 0) ? gl : gr;

    const int tid = threadIdx.x;

    {
        const int r = tid >> 6;
        const int kc = (tid & 63) * 4;
        *(float4*)&xs[r][kc] = *(const float4*)(x + (rowBase + r) * kC + kc);
    }
    __syncthreads();

    const int c0 = tid * 2;
    float acc[4][2];
#pragma unroll
    for (int r = 0; r < 4; ++r) { acc[r][0] = 0.f; acc[r][1] = 0.f; }

    float2 wv[4], wn[4];
#pragma unroll
    for (int kk = 0; kk < 4; ++kk)
        wv[kk] = *(const float2*)(Wm + kk * kHF + c0);

    for (int k = 0; k < kC; k += 4) {
        if (k + 4 < kC) {
#pragma unroll
            for (int kk = 0; kk < 4; ++kk)
                wn[kk] = *(const float2*)(Wm + (k + 4 + kk) * kHF + c0);
        }
#pragma unroll
        for (int r = 0; r < 4; ++r) {
            float4 xv = *(const float4*)&xs[r][k];
            acc[r][0] = fmaf(xv.x, wv[0].x, acc[r][0]);
            acc[r][1] = fmaf(xv.x, wv[0].y, acc[r][1]);
            acc[r][0] = fmaf(xv.y, wv[1].x, acc[r][0]);
            acc[r][1] = fmaf(xv.y, wv[1].y, acc[r][1]);
            acc[r][0] = fmaf(xv.z, wv[2].x, acc[r][0]);
            acc[r][1] = fmaf(xv.z, wv[2].y, acc[r][1]);
            acc[r][0] = fmaf(xv.w, wv[3].x, acc[r][0]);
            acc[r][1] = fmaf(xv.w, wv[3].y, acc[r][1]);
        }
#pragma unroll
        for (int kk = 0; kk < 4; ++kk) wv[kk] = wn[kk];
    }

#pragma unroll
    for (int r = 0; r < 4; ++r) {
        H2U p; p.h = (h2){(_Float16)acc[r][0], (_Float16)acc[r][1]};
        gout[((rowBase + r) * kHF + c0) >> 1] = p.u;
    }
}

// ---------------------------------------------------------------------------
// Phase B v3.1: lane owns (j_local, h) with the FULL f=64 row in registers.
// Block = 256 threads (4 waves) per (b,i) row; grid = B*N = 1024 -> 4
// blocks/CU, 4 waves/SIMD. lane = jl*8 + h; round r: j = r*32 + wv*8 + jl.
// e-dot: in-register fdot2 chain (zero f-reduce shuffles). Head softmax:
// 3 shuffles amortized over 8 j's. attn_w in SGPRs.
// CRITICAL (R8 lesson): every register-array index is STATIC — the epilogue
// lets only jl==0 lanes (which hold the fully jl-reduced acc after the
// butterfly) write their whole acc[] with a static unrolled loop. A dynamic
// acc[jl*4+k] in R8 demoted acc[] to scratch (VGPR_Count 60, 116 us).
// ---------------------------------------------------------------------------
__global__ __launch_bounds__(256, 4) void gat_attn_kernel(
    const unsigned int* __restrict__ gl,   // f16 pairs
    const unsigned int* __restrict__ gr,
    const float* __restrict__ attn_w,
    const int* __restrict__ adj,
    float* __restrict__ out)
{
    __shared__ float red[4][kHF];          // 8 KiB
    __shared__ unsigned char msk[kN];      // 256 B

    const int bi = blockIdx.x;             // b*N + i
    const int b = bi >> 8;
    const int i = bi & 255;
    const int tid = threadIdx.x;
    const int wv = tid >> 6;               // 0..3
    const int lane = tid & 63;
    const int jl = lane >> 3;              // 0..7
    const int h = lane & 7;                // 0..7

    // ---- pack adj -> LDS byte masks: msk[j] bit h = adj[i,j,h]!=0 ----
    {
        const int* ap = adj + (i * kN + tid) * kH;
        uint4 a0 = *(const uint4*)ap;
        uint4 a1 = *(const uint4*)(ap + 4);
        unsigned int m = 0;
        m |= (a0.x != 0) << 0; m |= (a0.y != 0) << 1;
        m |= (a0.z != 0) << 2; m |= (a0.w != 0) << 3;
        m |= (a1.x != 0) << 4; m |= (a1.y != 0) << 5;
        m |= (a1.z != 0) << 6; m |= (a1.w != 0) << 7;
        msk[tid] = (unsigned char)m;
    }

    // ---- gri: g_r[b, i, h, 0:64] -> 32 h2 regs (static indices only) ----
    h2 gri[32];
    {
        const uint4* gp = (const uint4*)(gr + (bi * 256 + h * 32));
#pragma unroll
        for (int q = 0; q < 8; ++q) {
            uint4 p = gp[q];
            H2U t;
            t.u = p.x; gri[q * 4 + 0] = t.h;
            t.u = p.y; gri[q * 4 + 1] = t.h;
            t.u = p.z; gri[q * 4 + 2] = t.h;
            t.u = p.w; gri[q * 4 + 3] = t.h;
        }
    }

    // ---- attn_w -> 32 packed-h2 SGPRs ----
    unsigned int wsg[32];
#pragma unroll
    for (int q = 0; q < 32; ++q) {
        float2 wp = *(const float2*)(attn_w + q * 2);
        H2U t; t.h = (h2){(_Float16)wp.x, (_Float16)wp.y};
        wsg[q] = __builtin_amdgcn_readfirstlane(t.u);
    }

    h2 acc[32];
#pragma unroll
    for (int q = 0; q < 32; ++q) acc[q] = (h2){(_Float16)0.f, (_Float16)0.f};

    const h2 c02 = (h2){(_Float16)0.2f, (_Float16)0.2f};

    __syncthreads();                       // msk ready

    unsigned int goff = (unsigned int)(b * kN * 256) + (wv * 8 + jl) * 256 + h * 32;
    int j = wv * 8 + jl;

    for (int round = 0; round < 8; ++round) {
        // ---- e-phase: stream g_l[b,j,h,0:64], fdot2 chain ----
        const uint4* gp = (const uint4*)(gl + goff);
        uint4 P[8];
#pragma unroll
        for (int q = 0; q < 8; ++q) P[q] = gp[q];

        float e = 0.f;
#pragma unroll
        for (int q = 0; q < 8; ++q) {
            H2U t0, t1, t2, t3, w0, w1, w2u, w3;
            t0.u = P[q].x; t1.u = P[q].y; t2.u = P[q].z; t3.u = P[q].w;
            w0.u = wsg[q * 4 + 0]; w1.u = wsg[q * 4 + 1];
            w2u.u = wsg[q * 4 + 2]; w3.u = wsg[q * 4 + 3];
            h2 s0 = gri[q * 4 + 0] + t0.h;
            h2 s1 = gri[q * 4 + 1] + t1.h;
            h2 s2 = gri[q * 4 + 2] + t2.h;
            h2 s3 = gri[q * 4 + 3] + t3.h;
            h2 u0 = __builtin_elementwise_max(s0, c02 * s0);
            h2 u1 = __builtin_elementwise_max(s1, c02 * s1);
            h2 u2 = __builtin_elementwise_max(s2, c02 * s2);
            h2 u3 = __builtin_elementwise_max(s3, c02 * s3);
            e = __builtin_amdgcn_fdot2(u0, w0.h, e, false);
            e = __builtin_amdgcn_fdot2(u1, w1.h, e, false);
            e = __builtin_amdgcn_fdot2(u2, w2u.h, e, false);
            e = __builtin_amdgcn_fdot2(u3, w3.h, e, false);
        }

        // ---- mask + head softmax (xor 1,2,4 over h lanes) ----
        const unsigned int mbit = ((unsigned int)msk[j] >> h) & 1u;
        e = mbit ? e : -1e30f;
        float ex = __expf(e);
        float den = ex;
        den += __shfl_xor(den, 1);
        den += __shfl_xor(den, 2);
        den += __shfl_xor(den, 4);
        float a = ex * __builtin_amdgcn_rcpf(den);
        h2 a2 = (h2){(_Float16)a, (_Float16)a};

        // ---- agg-phase: acc[f] += a * g_r[b,j,h,f] ----
        const uint4* gq = (const uint4*)(gr + goff);
#pragma unroll
        for (int q = 0; q < 8; ++q) {
            uint4 p = gq[q];
            H2U t0, t1, t2, t3;
            t0.u = p.x; t1.u = p.y; t2.u = p.z; t3.u = p.w;
            acc[q * 4 + 0] = __builtin_elementwise_fma(a2, t0.h, acc[q * 4 + 0]);
            acc[q * 4 + 1] = __builtin_elementwise_fma(a2, t1.h, acc[q * 4 + 1]);
            acc[q * 4 + 2] = __builtin_elementwise_fma(a2, t2.h, acc[q * 4 + 2]);
            acc[q * 4 + 3] = __builtin_elementwise_fma(a2, t3.h, acc[q * 4 + 3]);
        }

        goff += 32 * 256;
        j += 32;
    }

    // ---- butterfly-reduce acc over jl (lane bits 3,4,5), packed h2 ----
#pragma unroll
    for (int q = 0; q < 32; ++q) {
        H2U t; t.h = acc[q];
        H2U r;
        r.u = (unsigned int)__shfl_xor((int)t.u, 8);  t.h = t.h + r.h;
        r.u = (unsigned int)__shfl_xor((int)t.u, 16); t.h = t.h + r.h;
        r.u = (unsigned int)__shfl_xor((int)t.u, 32); t.h = t.h + r.h;
        acc[q] = t.h;
    }

    // After the butterfly all jl-lanes of a given h hold identical acc.
    // Only jl==0 lanes write the full f-row — STATIC indices into acc[].
    if (jl == 0) {
#pragma unroll
        for (int q = 0; q < 32; ++q) {
            h2 v = acc[q];
            float2 f = make_float2((float)v.x, (float)v.y);
            *(float2*)&red[wv][h * 64 + q * 2] = f;
        }
    }
    __syncthreads();

    // final: 512 outputs, 256 threads -> 2 per thread
#pragma unroll
    for (int c = tid; c < kHF; c += 256) {
        float s = red[0][c] + red[1][c] + red[2][c] + red[3][c];
        out[(size_t)bi * kHF + c] = s;
    }
}

// ---------------------------------------------------------------------------
extern "C" void kernel_launch(void* const* d_in, const int* in_sizes, int n_in,
                              void* d_out, int out_size, void* d_ws, size_t ws_size,
                              hipStream_t stream) {
    const float* x  = (const float*)d_in[0];
    const float* Wl = (const float*)d_in[1];
    const float* Wr = (const float*)d_in[2];
    const float* aw = (const float*)d_in[3];
    const int* adj  = (const int*)d_in[4];

    unsigned int* gl = (unsigned int*)d_ws;                    // [B*N*HF/2]
    unsigned int* gr = gl + (size_t)kB * kN * kHF / 2;

    dim3 g1(kB * kN / 4, 2);
    gat_gemm_kernel<<<g1, 256, 0, stream>>>(x, Wl, Wr, gl, gr);

    gat_attn_kernel<<<kB * kN, 256, 0, stream>>>(
        gl, gr, aw, adj, (float*)d_out);
}

// Round 10
// 110.980 us; speedup vs baseline: 1.7263x; 1.6836x over previous
//
#include <hip/hip_runtime.h>
#include <hip/hip_bf16.h>

typedef _Float16 h2 __attribute__((ext_vector_type(2)));

constexpr int kB = 4, kN = 256, kC = 256, kH = 8, kF = 64, kHF = 512;
constexpr int kIPB = 4;   // attention rows (i) per block

union H2U { h2 h; unsigned int u; };

// ---------------------------------------------------------------------------
// Phase A: g = x @ W  (fp32 in, f16 out to ws). W selected by blockIdx.y.
// R5's proven version: LDS-staged x, W software-pipelined.
// Block: 256 threads, 4 rows x 512 cols. Grid: (256, 2).
// ---------------------------------------------------------------------------
__global__ __launch_bounds__(256) void gat_gemm_kernel(
    const float* __restrict__ x,
    const float* __restrict__ Wl,
    const float* __restrict__ Wr,
    unsigned int* __restrict__ gl,    // f16 pairs
    unsigned int* __restrict__ gr)
{
    __shared__ float xs[4][kC];   // 4 KiB
    const int rowBase = blockIdx.x * 4;
    const float* Wm = (blockIdx.y == 0) ? Wl : Wr;
    unsigned int* gout = (blockIdx.y == 0) ? gl : gr;

    const int tid = threadIdx.x;

    {
        const int r = tid >> 6;
        const int kc = (tid & 63) * 4;
        *(float4*)&xs[r][kc] = *(const float4*)(x + (rowBase + r) * kC + kc);
    }
    __syncthreads();

    const int c0 = tid * 2;
    float acc[4][2];
#pragma unroll
    for (int r = 0; r < 4; ++r) { acc[r][0] = 0.f; acc[r][1] = 0.f; }

    float2 wv[4], wn[4];
#pragma unroll
    for (int kk = 0; kk < 4; ++kk)
        wv[kk] = *(const float2*)(Wm + kk * kHF + c0);

    for (int k = 0; k < kC; k += 4) {
        if (k + 4 < kC) {
#pragma unroll
            for (int kk = 0; kk < 4; ++kk)
                wn[kk] = *(const float2*)(Wm + (k + 4 + kk) * kHF + c0);
        }
#pragma unroll
        for (int r = 0; r < 4; ++r) {
            float4 xv = *(const float4*)&xs[r][k];
            acc[r][0] = fmaf(xv.x, wv[0].x, acc[r][0]);
            acc[r][1] = fmaf(xv.x, wv[0].y, acc[r][1]);
            acc[r][0] = fmaf(xv.y, wv[1].x, acc[r][0]);
            acc[r][1] = fmaf(xv.y, wv[1].y, acc[r][1]);
            acc[r][0] = fmaf(xv.z, wv[2].x, acc[r][0]);
            acc[r][1] = fmaf(xv.z, wv[2].y, acc[r][1]);
            acc[r][0] = fmaf(xv.w, wv[3].x, acc[r][0]);
            acc[r][1] = fmaf(xv.w, wv[3].y, acc[r][1]);
        }
#pragma unroll
        for (int kk = 0; kk < 4; ++kk) wv[kk] = wn[kk];
    }

#pragma unroll
    for (int r = 0; r < 4; ++r) {
        H2U p; p.h = (h2){(_Float16)acc[r][0], (_Float16)acc[r][1]};
        gout[((rowBase + r) * kHF + c0) >> 1] = p.u;
    }
}

// ---------------------------------------------------------------------------
// Phase B (R5 structure + R6's proven msk/h2-acc): 1024 thr = 16 waves,
// kIPB=4 rows per block, grid 256. Wave wv handles j = wv, wv+16, ...
// lane = h*8+fg; whole wave reads ONE contiguous 1 KiB j-row per load
// (the coalesced layout — R8/R9's 128B-stride gather was 64 lines/inst).
// adj pre-packed to LDS u32 bitmasks (broadcast ds_read, no global loads
// in the j-loop). Packed-h2 accumulators; 2-stage reduction in packed h2
// (red = 32 KiB, + 1 KiB msk; VGPR ~60 -> 2 blocks/CU, 8 waves/SIMD).
// ---------------------------------------------------------------------------
__global__ __launch_bounds__(1024, 4) void gat_attn_kernel(
    const unsigned int* __restrict__ gl,   // f16 pairs
    const unsigned int* __restrict__ gr,
    const float* __restrict__ attn_w,
    const int* __restrict__ adj,
    float* __restrict__ out)
{
    __shared__ unsigned int red[8 * kIPB * 256];  // 32 KiB (packed h2)
    __shared__ unsigned int msk[kN];              // 1 KiB

    const int bi0 = blockIdx.x * kIPB;     // first row (b*N + i)
    const int b = bi0 >> 8;
    const int i0 = bi0 & 255;
    const int tid = threadIdx.x;
    const int wv = tid >> 6;               // 0..15
    const int lane = tid & 63;
    const int h = lane >> 3;
    const int fg = lane & 7;

    // ---- pack adj -> LDS bitmasks: msk[j] = 4 ii-bytes of 8 h-bits ----
    {
        const int j = tid & 255;
        const int ii = tid >> 8;
        const int* ap = adj + (i0 + ii) * (kN * kH) + j * kH;
        uint4 a0 = *(const uint4*)ap;
        uint4 a1 = *(const uint4*)(ap + 4);
        unsigned int m = 0;
        m |= (a0.x != 0) << 0; m |= (a0.y != 0) << 1;
        m |= (a0.z != 0) << 2; m |= (a0.w != 0) << 3;
        m |= (a1.x != 0) << 4; m |= (a1.y != 0) << 5;
        m |= (a1.z != 0) << 6; m |= (a1.w != 0) << 7;
        ((unsigned char*)msk)[j * 4 + ii] = (unsigned char)m;
    }

    // ---- preload g_r[b, i0+ii, h, fg*8..+7] and attn_w as h2 ----
    h2 gri[kIPB][4];
#pragma unroll
    for (int ii = 0; ii < kIPB; ++ii) {
        uint4 pk = *(const uint4*)(gr + ((bi0 + ii) * 256 + h * 32 + fg * 4));
        H2U a0, a1, a2, a3;
        a0.u = pk.x; a1.u = pk.y; a2.u = pk.z; a3.u = pk.w;
        gri[ii][0] = a0.h; gri[ii][1] = a1.h; gri[ii][2] = a2.h; gri[ii][3] = a3.h;
    }
    h2 w2[4];
    {
        float4 wa = *(const float4*)(attn_w + fg * 8);
        float4 wb = *(const float4*)(attn_w + fg * 8 + 4);
        w2[0] = (h2){(_Float16)wa.x, (_Float16)wa.y};
        w2[1] = (h2){(_Float16)wa.z, (_Float16)wa.w};
        w2[2] = (h2){(_Float16)wb.x, (_Float16)wb.y};
        w2[3] = (h2){(_Float16)wb.z, (_Float16)wb.w};
    }

    h2 acc[kIPB][4];
#pragma unroll
    for (int ii = 0; ii < kIPB; ++ii)
#pragma unroll
        for (int q = 0; q < 4; ++q) acc[ii][q] = (h2){(_Float16)0.f, (_Float16)0.f};

    const h2 c02 = (h2){(_Float16)0.2f, (_Float16)0.2f};

    __syncthreads();                       // msk ready

    // 32-bit uint offsets; stride per j = 256 uints (1 KiB row)
    unsigned int goff = (unsigned int)(b * (kN * 256) + wv * 256
                                       + h * 32 + fg * 4);

    // software-pipelined loads
    uint4 ga = *(const uint4*)(gl + goff);
    uint4 gb = *(const uint4*)(gr + goff);

    for (int it = 0; it < 16; ++it) {
        const int j = wv + it * 16;
        // prefetch next j-row (tail reads in-bounds scratch; discarded)
        const unsigned int offn = goff + 16 * 256;
        uint4 ga_n = *(const uint4*)(gl + offn);
        uint4 gb_n = *(const uint4*)(gr + offn);
        goff = offn;

        const unsigned int m = msk[j];                // LDS broadcast

        h2 gl2[4], gr2[4];
        { H2U t; t.u = ga.x; gl2[0] = t.h; t.u = ga.y; gl2[1] = t.h;
                 t.u = ga.z; gl2[2] = t.h; t.u = ga.w; gl2[3] = t.h;
                 t.u = gb.x; gr2[0] = t.h; t.u = gb.y; gr2[1] = t.h;
                 t.u = gb.z; gr2[2] = t.h; t.u = gb.w; gr2[3] = t.h; }

#pragma unroll
        for (int ii = 0; ii < kIPB; ++ii) {
            float e = 0.f;
#pragma unroll
            for (int q = 0; q < 4; ++q) {
                h2 s = gri[ii][q] + gl2[q];
                h2 u = __builtin_elementwise_max(s, c02 * s);  // leaky 0.2
                e = __builtin_amdgcn_fdot2(u, w2[q], e, false);
            }
            // reduce over fg (lane bits 0..2)
            e += __shfl_xor(e, 1);
            e += __shfl_xor(e, 2);
            e += __shfl_xor(e, 4);

            const unsigned int bit = (m >> (ii * 8 + h)) & 1u;
            e = bit ? e : -1e30f;

            float ex = __expf(e);
            float den = ex;
            den += __shfl_xor(den, 8);
            den += __shfl_xor(den, 16);
            den += __shfl_xor(den, 32);
            float a = ex * __builtin_amdgcn_rcpf(den);

            const h2 a2 = (h2){(_Float16)a, (_Float16)a};
#pragma unroll
            for (int q = 0; q < 4; ++q)
                acc[ii][q] = __builtin_elementwise_fma(a2, gr2[q], acc[ii][q]);
        }

        ga = ga_n; gb = gb_n;
    }

    // -------- two-stage cross-wave reduction (16 -> 8 -> 1), packed h2 ----
    // element pair-index for acc[ii][q]: h*32 + fg*4 + q  (0..255)
    const int ep = h * 32 + fg * 4;
    if (wv >= 8) {
#pragma unroll
        for (int ii = 0; ii < kIPB; ++ii) {
            unsigned int* rp = &red[((wv - 8) * kIPB + ii) * 256 + ep];
#pragma unroll
            for (int q = 0; q < 4; ++q) { H2U t; t.h = acc[ii][q]; rp[q] = t.u; }
        }
    }
    __syncthreads();
    if (wv < 8) {
#pragma unroll
        for (int ii = 0; ii < kIPB; ++ii) {
            unsigned int* rp = &red[(wv * kIPB + ii) * 256 + ep];
#pragma unroll
            for (int q = 0; q < 4; ++q) {
                H2U t; t.u = rp[q];
                t.h = t.h + acc[ii][q];
                rp[q] = t.u;
            }
        }
    }
    __syncthreads();

    // final: kIPB rows x 256 pair-columns; thread t -> (ii = t>>8, cp = t&255)
    {
        const int ii = tid >> 8;
        const int cp = tid & 255;
        float2 s = make_float2(0.f, 0.f);
#pragma unroll
        for (int p = 0; p < 8; ++p) {
            H2U t; t.u = red[(p * kIPB + ii) * 256 + cp];
            s.x += (float)t.h.x;
            s.y += (float)t.h.y;
        }
        *(float2*)&out[(bi0 + ii) * kHF + cp * 2] = s;
    }
}

// ---------------------------------------------------------------------------
extern "C" void kernel_launch(void* const* d_in, const int* in_sizes, int n_in,
                              void* d_out, int out_size, void* d_ws, size_t ws_size,
                              hipStream_t stream) {
    const float* x  = (const float*)d_in[0];
    const float* Wl = (const float*)d_in[1];
    const float* Wr = (const float*)d_in[2];
    const float* aw = (const float*)d_in[3];
    const int* adj  = (const int*)d_in[4];

    unsigned int* gl = (unsigned int*)d_ws;                    // [B*N*HF/2]
    unsigned int* gr = gl + (size_t)kB * kN * kHF / 2;

    dim3 g1(kB * kN / 4, 2);
    gat_gemm_kernel<<<g1, 256, 0, stream>>>(x, Wl, Wr, gl, gr);

    gat_attn_kernel<<<kB * kN / kIPB, 1024, 0, stream>>>(
        gl, gr, aw, adj, (float*)d_out);
}